// Round 1
// baseline (961.827 us; speedup 1.0000x reference)
//
#include <hip/hip_runtime.h>
#include <cmath>

#define BN 2
#define AN 3
#define SN 8
#define CN 20
#define IMGN 256
#define NSTEP 384   // A*S*S*B steps in scan order (k,i,j,b)
#define PRED_C 26   // 6 + C

struct WS {
  unsigned meta[NSTEP];  // b | valid<<8
  float    lv[NSTEP];    // log(max(1, v))
  unsigned fx[NSTEP];    // full rect row bounds:  xlo | xhi<<16  (from cx,w !)
  unsigned fy[NSTEP];    // full rect col bounds:  ylo | yhi<<16  (from cy,h !)
  unsigned sx[NSTEP];    // small rect row bounds
  unsigned sy[NSTEP];    // small rect col bounds
  float    yolo[8];      // [sum_objf, bce_sum, bce_cnt, obj_sum, box_sum, cls_sum]
};

__device__ __forceinline__ float wredf(float v){
  #pragma unroll
  for (int o = 32; o; o >>= 1) v += __shfl_xor(v, o);
  return v;
}
__device__ __forceinline__ double wredd(double v){
  #pragma unroll
  for (int o = 32; o; o >>= 1) v += __shfl_xor(v, o);
  return v;
}
__device__ __forceinline__ int finitef(float x){
  return (__float_as_uint(x) & 0x7f800000u) != 0x7f800000u;
}
// exact replica of reference _axis_mask index computation (f32 trunc + negative wrap)
__device__ __forceinline__ unsigned axism(float lo, float hi){
  float lof = truncf(fminf(fmaxf(lo, -1e9f), 1e9f));
  float hif = truncf(fminf(fmaxf(hi, -1e9f), 1e9f));
  int l = (int)lof, h = (int)hif;
  l = (l < 0) ? max(IMGN + l, 0) : min(l, IMGN);
  h = (h < 0) ? max(IMGN + h, 0) : min(h, IMGN);
  return (unsigned)l | ((unsigned)h << 16);
}

// ---------------- Kernel A: per-step params + YOLO loss partials ----------------
__global__ __launch_bounds__(384) void yolo_kA(const float* __restrict__ pred,
                                               const float* __restrict__ tgt,
                                               const float* __restrict__ anc,
                                               WS* __restrict__ ws){
  int tid = threadIdx.x;

  // ---- step parameters; scan order t = ((k*S + i)*S + j)*B + b ----
  {
    int t = tid;
    int b = t % BN;
    int j = (t / BN) % SN;
    int i = (t / (BN * SN)) % SN;
    int k = t / (BN * SN * SN);
    const float* pc = pred + (size_t)((((b * AN + k) * SN + i) * SN + j)) * PRED_C;
    float x = pc[1], y = pc[2], wv = pc[3], hv = pc[4], v = pc[5];
    float aw = anc[2 * k], ah = anc[2 * k + 1];
    // xy gets sigmoid applied (k+2) times total (1 before loop + k+1 in loop)
    for (int m = 0; m < k + 2; ++m) {
      x = 1.0f / (1.0f + expf(-x));
      y = 1.0f / (1.0f + expf(-y));
    }
    // wh: (k+1) iterations of exp(.)*anchor[k], in f32 (overflow -> inf -> invalid)
    for (int m = 0; m < k + 1; ++m) {
      wv = expf(wv) * aw;
      hv = expf(hv) * ah;
    }
    float cx = (x + (float)j) / 8.0f * 256.0f;
    float cy = (y + (float)i) / 8.0f * 256.0f;
    float w  = wv / 8.0f * 256.0f;
    float h  = hv / 8.0f * 256.0f;
    int valid = (w > 0.0f) && (h > 0.0f) && finitef(w) && finitef(h);
    float val = fmaxf(1.0f, v);
    ws->lv[t]   = logf(val);
    ws->meta[t] = (unsigned)b | ((unsigned)valid << 8);
    // NOTE reference quirk: x-mask (from cx,w) indexes dp's ROW axis, y-mask the COL axis
    ws->fx[t] = axism(cx - w / 2.0f, cx + w / 2.0f);
    ws->fy[t] = axism(cy - h / 2.0f, cy + h / 2.0f);
    ws->sx[t] = axism(cx - w / 4.0f, cx + w / 4.0f);
    ws->sy[t] = axism(cy - h / 4.0f, cy + h / 4.0f);
  }

  // ---- YOLO losses; cell order (b,a,i,j) ----
  float s_obj, s_bce, s_bcecnt, s_objls, s_boxls, s_clsls;
  {
    int t = tid;
    int j = t % SN;
    int i = (t / SN) % SN;
    int a = (t / (SN * SN)) % AN;
    int b = t / (SN * SN * AN);
    const float* pc = pred + (size_t)((((b * AN + a) * SN + i) * SN + j)) * PRED_C;
    const float* tc = tgt  + (size_t)((((b * AN + a) * SN + i) * SN + j)) * 6;
    float t0 = tc[0];
    float objf  = (t0 == 1.0f) ? 1.0f : 0.0f;
    float noobj = (t0 == 0.0f) ? 1.0f : 0.0f;
    float p0 = pc[0];
    float l = fmaxf(p0, 0.0f) - p0 * t0 + log1pf(expf(-fabsf(p0)));
    s_bce = l * noobj; s_bcecnt = noobj; s_obj = objf;
    float aw = anc[2 * a], ah = anc[2 * a + 1];
    float sxp = 1.0f / (1.0f + expf(-pc[1]));
    float syp = 1.0f / (1.0f + expf(-pc[2]));
    float bw = expf(pc[3]) * aw, bh = expf(pc[4]) * ah;
    float ax1 = sxp - bw * 0.5f, ax2 = sxp + bw * 0.5f;
    float ay1 = syp - bh * 0.5f, ay2 = syp + bh * 0.5f;
    float bx1 = tc[1] - tc[3] * 0.5f, bx2 = tc[1] + tc[3] * 0.5f;
    float by1 = tc[2] - tc[4] * 0.5f, by2 = tc[2] + tc[4] * 0.5f;
    float iw = fmaxf(fminf(ax2, bx2) - fmaxf(ax1, bx1), 0.0f);
    float ih = fmaxf(fminf(ay2, by2) - fmaxf(ay1, by1), 0.0f);
    float inter = iw * ih;
    float areaA = fabsf((ax2 - ax1) * (ay2 - ay1));
    float areaB = fabsf((bx2 - bx1) * (by2 - by1));
    float iou = inter / (areaA + areaB - inter + 1e-6f);
    float sp0 = 1.0f / (1.0f + expf(-p0));
    float od = sp0 - iou * t0;
    s_objls = od * od * objf;
    float dx = sxp - tc[1], dy = syp - tc[2];
    float dw = pc[3] - logf(1e-16f + tc[3] / aw);
    float dh = pc[4] - logf(1e-16f + tc[4] / ah);
    s_boxls = (dx * dx + dy * dy + dw * dw + dh * dh) * objf;
    int lbl = (int)tc[5];
    float mx = -INFINITY;
    for (int c = 0; c < CN; ++c) mx = fmaxf(mx, pc[6 + c]);
    float se = 0.0f;
    for (int c = 0; c < CN; ++c) se += expf(pc[6 + c] - mx);
    float nll = mx + logf(se) - pc[6 + lbl];
    s_clsls = nll * objf;
  }

  __shared__ float ry[6 * 6];
  int wv = tid >> 6, ln = tid & 63;
  float vals[6] = { s_obj, s_bce, s_bcecnt, s_objls, s_boxls, s_clsls };
  #pragma unroll
  for (int ci = 0; ci < 6; ++ci) {
    float v = wredf(vals[ci]);
    if (ln == 0) ry[ci * 6 + wv] = v;
  }
  __syncthreads();
  if (tid == 0) {
    #pragma unroll
    for (int ci = 0; ci < 6; ++ci) {
      float s = 0.0f;
      for (int w2 = 0; w2 < 6; ++w2) s += ry[ci * 6 + w2];
      ws->yolo[ci] = s;
    }
  }
}

// ---------------- Kernel B: per-pixel step scan -> per-step delta partials ----------------
__global__ __launch_bounds__(256) void yolo_kB(const float* __restrict__ depth,
                                               const WS* __restrict__ ws,
                                               float* __restrict__ scratch){
  __shared__ unsigned s_meta[NSTEP];
  __shared__ float    s_lv[NSTEP];
  __shared__ unsigned s_fx[NSTEP], s_fy[NSTEP], s_sx[NSTEP], s_sy[NSTEP];
  __shared__ float    acc[NSTEP * 6];
  int tid = threadIdx.x;
  for (int e = tid; e < NSTEP; e += 256) {
    s_meta[e] = ws->meta[e]; s_lv[e] = ws->lv[e];
    s_fx[e] = ws->fx[e]; s_fy[e] = ws->fy[e];
    s_sx[e] = ws->sx[e]; s_sy[e] = ws->sy[e];
  }
  for (int e = tid; e < NSTEP * 6; e += 256) acc[e] = 0.0f;
  __syncthreads();

  int c = tid;           // column = lane-contiguous
  int ln = tid & 63;
  for (int ru = blockIdx.x; ru < BN * IMGN; ru += gridDim.x) {
    int b = ru >> 8;     // row unit: b*256 + r
    int r = ru & 255;
    float dt = depth[(size_t)ru * IMGN + c];
    bool ok = dt >= 1.0f;
    float ldt = ok ? logf(dt) : 0.0f;
    bool hF = false, hS = false;
    float lvF = 0.0f, lvS = 0.0f;
    for (int t = 0; t < NSTEP; ++t) {
      unsigned mt = s_meta[t];
      if ((int)(mt & 0xff) != b || !(mt >> 8)) continue;     // wave-uniform skip
      unsigned fx = s_fx[t], sx = s_sx[t];
      bool rowF = (r >= (int)(fx & 0xffff)) && (r < (int)(fx >> 16));
      bool rowS = (r >= (int)(sx & 0xffff)) && (r < (int)(sx >> 16));
      if (!rowF && !rowS) continue;                           // wave-uniform skip
      unsigned fy = s_fy[t], sy = s_sy[t];
      float lv = s_lv[t];
      bool inF = ok && rowF && (c >= (int)(fy & 0xffff)) && (c < (int)(fy >> 16));
      bool inS = ok && rowS && (c >= (int)(sy & 0xffff)) && (c < (int)(sy >> 16));
      if (__ballot(inF || inS) == 0ull) continue;
      float d0 = 0.f, d1 = 0.f, d2 = 0.f, e0 = 0.f, e1 = 0.f, e2 = 0.f;
      if (inF) {
        float gn = lv - ldt;
        if (hF) { float go = lvF - ldt; d1 = lv - lvF; d2 = gn * gn - go * go; }
        else    { d0 = 1.0f; d1 = gn; d2 = gn * gn; hF = true; }
        lvF = lv;
      }
      if (inS) {
        float gn = lv - ldt;
        if (hS) { float go = lvS - ldt; e1 = lv - lvS; e2 = gn * gn - go * go; }
        else    { e0 = 1.0f; e1 = gn; e2 = gn * gn; hS = true; }
        lvS = lv;
      }
      d0 = wredf(d0); d1 = wredf(d1); d2 = wredf(d2);
      e0 = wredf(e0); e1 = wredf(e1); e2 = wredf(e2);
      if (ln == 0) {
        atomicAdd(&acc[t * 6 + 0], d0); atomicAdd(&acc[t * 6 + 1], d1); atomicAdd(&acc[t * 6 + 2], d2);
        atomicAdd(&acc[t * 6 + 3], e0); atomicAdd(&acc[t * 6 + 4], e1); atomicAdd(&acc[t * 6 + 5], e2);
      }
    }
  }
  __syncthreads();
  float* out = scratch + (size_t)blockIdx.x * (NSTEP * 6);
  for (int e = tid; e < NSTEP * 6; e += 256) out[e] = acc[e];
}

// ---------------- Kernel C: reduce partials, prefix over steps, final loss ----------------
__global__ __launch_bounds__(384) void yolo_kC(const WS* __restrict__ ws,
                                               const float* __restrict__ scratch,
                                               int nblocks,
                                               float* __restrict__ out){
  __shared__ double sd[NSTEP * 6];
  __shared__ double chunk[6 * 6];     // [chunkIdx][comp], chunks of 64 steps
  __shared__ double rl[6], rc[6];
  int tid = threadIdx.x;
  for (int e = tid; e < NSTEP * 6; e += 384) {
    double s = 0.0;
    for (int bk = 0; bk < nblocks; ++bk) s += (double)scratch[(size_t)bk * (NSTEP * 6) + e];
    sd[e] = s;
  }
  __syncthreads();
  if (tid < 36) {
    int ch = tid / 6, comp = tid % 6;
    double s = 0.0;
    for (int t = ch * 64; t < ch * 64 + 64; ++t) s += sd[t * 6 + comp];
    chunk[tid] = s;
  }
  __syncthreads();

  int t = tid;
  int ch = t >> 6;
  double P[6];
  #pragma unroll
  for (int comp = 0; comp < 6; ++comp) {
    double s = 0.0;
    for (int cc = 0; cc < ch; ++cc) s += chunk[cc * 6 + comp];
    for (int tt = (ch << 6); tt <= t; ++tt) s += sd[tt * 6 + comp];
    P[comp] = s;   // inclusive prefix: sums AFTER step t's paint
  }
  bool valid = ((ws->meta[t] >> 8) & 1u) != 0u;
  double lossd = 0.0, cntd = 0.0;
  {
    double n = P[0], Sg = P[1], Sg2 = P[2];
    double mean = Sg / fmax(n, 1.0);
    double var = (Sg2 - 2.0 * mean * Sg + n * mean * mean) / fmax(n - 1.0, 1.0);
    double Dg = var + 0.15 * mean * mean;
    double pl = 10.0 * sqrt(fmax(Dg, 1e-30));
    if (valid && n >= 2.0) { lossd += pl; cntd += 1.0; }
  }
  {
    double n = P[3], Sg = P[4], Sg2 = P[5];
    double mean = Sg / fmax(n, 1.0);
    double var = (Sg2 - 2.0 * mean * Sg + n * mean * mean) / fmax(n - 1.0, 1.0);
    double Dg = var + 0.15 * mean * mean;
    double pl = 10.0 * sqrt(fmax(Dg, 1e-30));
    if (valid && n >= 2.0) { lossd += pl; cntd += 1.0; }
  }
  int wv = tid >> 6, ln = tid & 63;
  double L = wredd(lossd), C = wredd(cntd);
  if (ln == 0) { rl[wv] = L; rc[wv] = C; }
  __syncthreads();
  if (tid == 0) {
    double totL = 0.0, totC = 0.0;
    for (int i = 0; i < 6; ++i) { totL += rl[i]; totC += rc[i]; }
    float dl = (float)(totL / fmax(totC, 1.0));
    float nobj = fmaxf(ws->yolo[0], 1.0f);
    float noo  = ws->yolo[1] / fmaxf(ws->yolo[2], 1.0f);
    float objl = ws->yolo[3] / nobj;
    float boxl = ws->yolo[4] / (nobj * 4.0f);
    float clsl = ws->yolo[5] / nobj;
    out[0] = 10.0f * boxl + objl + 10.0f * noo + clsl + dl;
  }
}

extern "C" void kernel_launch(void* const* d_in, const int* in_sizes, int n_in,
                              void* d_out, int out_size, void* d_ws, size_t ws_size,
                              hipStream_t stream) {
  const float* pred  = (const float*)d_in[0];
  const float* tgt   = (const float*)d_in[1];
  const float* anc   = (const float*)d_in[2];
  const float* depth = (const float*)d_in[3];
  WS* ws = (WS*)d_ws;
  size_t wsHead = ((sizeof(WS) + 255) / 256) * 256;
  float* scratch = (float*)((char*)d_ws + wsHead);
  long long avail = (long long)ws_size - (long long)wsHead;
  int maxb = (int)(avail / (long long)(NSTEP * 6 * sizeof(float)));
  int nblocks = maxb < 512 ? maxb : 512;
  if (nblocks < 1) nblocks = 1;

  hipLaunchKernelGGL(yolo_kA, dim3(1), dim3(384), 0, stream, pred, tgt, anc, ws);
  hipLaunchKernelGGL(yolo_kB, dim3(nblocks), dim3(256), 0, stream, depth, ws, scratch);
  hipLaunchKernelGGL(yolo_kC, dim3(1), dim3(384), 0, stream, ws, scratch, nblocks, (float*)d_out);
}

// Round 2
// 186.210 us; speedup vs baseline: 5.1653x; 5.1653x over previous
//
#include <hip/hip_runtime.h>
#include <cmath>

#define BN 2
#define AN 3
#define SN 8
#define CN 20
#define IMGN 256
#define NSTEP 384   // A*S*S*B steps in scan order (k,i,j,b)
#define PRED_C 26   // 6 + C
#define NE (NSTEP * 6)
#define NBMAX 512

struct WS {
  unsigned meta[NSTEP];  // b | valid<<8
  float    lv[NSTEP];    // log(max(1, v))
  unsigned fx[NSTEP];    // full rect row bounds:  xlo | xhi<<16  (from cx,w !)
  unsigned fy[NSTEP];    // full rect col bounds:  ylo | yhi<<16  (from cy,h !)
  unsigned sx[NSTEP];    // small rect row bounds
  unsigned sy[NSTEP];    // small rect col bounds
  float    yolo[8];      // [sum_objf, bce_sum, bce_cnt, obj_sum, box_sum, cls_sum]
};

__device__ __forceinline__ float wredf(float v){
  #pragma unroll
  for (int o = 32; o; o >>= 1) v += __shfl_xor(v, o);
  return v;
}
__device__ __forceinline__ double wredd(double v){
  #pragma unroll
  for (int o = 32; o; o >>= 1) v += __shfl_xor(v, o);
  return v;
}
__device__ __forceinline__ int finitef(float x){
  return (__float_as_uint(x) & 0x7f800000u) != 0x7f800000u;
}
// exact replica of reference _axis_mask index computation (f32 trunc + negative wrap)
__device__ __forceinline__ unsigned axism(float lo, float hi){
  float lof = truncf(fminf(fmaxf(lo, -1e9f), 1e9f));
  float hif = truncf(fminf(fmaxf(hi, -1e9f), 1e9f));
  int l = (int)lof, h = (int)hif;
  l = (l < 0) ? max(IMGN + l, 0) : min(l, IMGN);
  h = (h < 0) ? max(IMGN + h, 0) : min(h, IMGN);
  return (unsigned)l | ((unsigned)h << 16);
}

// ---------------- Kernel A: per-step params + YOLO loss partials ----------------
__global__ __launch_bounds__(384) void yolo_kA(const float* __restrict__ pred,
                                               const float* __restrict__ tgt,
                                               const float* __restrict__ anc,
                                               WS* __restrict__ ws){
  int tid = threadIdx.x;

  // ---- step parameters; scan order t = ((k*S + i)*S + j)*B + b ----
  {
    int t = tid;
    int b = t % BN;
    int j = (t / BN) % SN;
    int i = (t / (BN * SN)) % SN;
    int k = t / (BN * SN * SN);
    const float* pc = pred + (size_t)((((b * AN + k) * SN + i) * SN + j)) * PRED_C;
    float x = pc[1], y = pc[2], wv = pc[3], hv = pc[4], v = pc[5];
    float aw = anc[2 * k], ah = anc[2 * k + 1];
    // xy gets sigmoid applied (k+2) times total (1 before loop + k+1 in loop)
    for (int m = 0; m < k + 2; ++m) {
      x = 1.0f / (1.0f + expf(-x));
      y = 1.0f / (1.0f + expf(-y));
    }
    // wh: (k+1) iterations of exp(.)*anchor[k], in f32 (overflow -> inf -> invalid)
    for (int m = 0; m < k + 1; ++m) {
      wv = expf(wv) * aw;
      hv = expf(hv) * ah;
    }
    float cx = (x + (float)j) / 8.0f * 256.0f;
    float cy = (y + (float)i) / 8.0f * 256.0f;
    float w  = wv / 8.0f * 256.0f;
    float h  = hv / 8.0f * 256.0f;
    int valid = (w > 0.0f) && (h > 0.0f) && finitef(w) && finitef(h);
    float val = fmaxf(1.0f, v);
    ws->lv[t]   = logf(val);
    ws->meta[t] = (unsigned)b | ((unsigned)valid << 8);
    // NOTE reference quirk: x-mask (from cx,w) indexes dp's ROW axis, y-mask the COL axis
    ws->fx[t] = axism(cx - w / 2.0f, cx + w / 2.0f);
    ws->fy[t] = axism(cy - h / 2.0f, cy + h / 2.0f);
    ws->sx[t] = axism(cx - w / 4.0f, cx + w / 4.0f);
    ws->sy[t] = axism(cy - h / 4.0f, cy + h / 4.0f);
  }

  // ---- YOLO losses; cell order (b,a,i,j) ----
  float s_obj, s_bce, s_bcecnt, s_objls, s_boxls, s_clsls;
  {
    int t = tid;
    int j = t % SN;
    int i = (t / SN) % SN;
    int a = (t / (SN * SN)) % AN;
    int b = t / (SN * SN * AN);
    const float* pc = pred + (size_t)((((b * AN + a) * SN + i) * SN + j)) * PRED_C;
    const float* tc = tgt  + (size_t)((((b * AN + a) * SN + i) * SN + j)) * 6;
    float t0 = tc[0];
    float objf  = (t0 == 1.0f) ? 1.0f : 0.0f;
    float noobj = (t0 == 0.0f) ? 1.0f : 0.0f;
    float p0 = pc[0];
    float l = fmaxf(p0, 0.0f) - p0 * t0 + log1pf(expf(-fabsf(p0)));
    s_bce = l * noobj; s_bcecnt = noobj; s_obj = objf;
    float aw = anc[2 * a], ah = anc[2 * a + 1];
    float sxp = 1.0f / (1.0f + expf(-pc[1]));
    float syp = 1.0f / (1.0f + expf(-pc[2]));
    float bw = expf(pc[3]) * aw, bh = expf(pc[4]) * ah;
    float ax1 = sxp - bw * 0.5f, ax2 = sxp + bw * 0.5f;
    float ay1 = syp - bh * 0.5f, ay2 = syp + bh * 0.5f;
    float bx1 = tc[1] - tc[3] * 0.5f, bx2 = tc[1] + tc[3] * 0.5f;
    float by1 = tc[2] - tc[4] * 0.5f, by2 = tc[2] + tc[4] * 0.5f;
    float iw = fmaxf(fminf(ax2, bx2) - fmaxf(ax1, bx1), 0.0f);
    float ih = fmaxf(fminf(ay2, by2) - fmaxf(ay1, by1), 0.0f);
    float inter = iw * ih;
    float areaA = fabsf((ax2 - ax1) * (ay2 - ay1));
    float areaB = fabsf((bx2 - bx1) * (by2 - by1));
    float iou = inter / (areaA + areaB - inter + 1e-6f);
    float sp0 = 1.0f / (1.0f + expf(-p0));
    float od = sp0 - iou * t0;
    s_objls = od * od * objf;
    float dx = sxp - tc[1], dy = syp - tc[2];
    float dw = pc[3] - logf(1e-16f + tc[3] / aw);
    float dh = pc[4] - logf(1e-16f + tc[4] / ah);
    s_boxls = (dx * dx + dy * dy + dw * dw + dh * dh) * objf;
    int lbl = (int)tc[5];
    float mx = -INFINITY;
    for (int c = 0; c < CN; ++c) mx = fmaxf(mx, pc[6 + c]);
    float se = 0.0f;
    for (int c = 0; c < CN; ++c) se += expf(pc[6 + c] - mx);
    float nll = mx + logf(se) - pc[6 + lbl];
    s_clsls = nll * objf;
  }

  __shared__ float ry[6 * 6];
  int wv = tid >> 6, ln = tid & 63;
  float vals[6] = { s_obj, s_bce, s_bcecnt, s_objls, s_boxls, s_clsls };
  #pragma unroll
  for (int ci = 0; ci < 6; ++ci) {
    float v = wredf(vals[ci]);
    if (ln == 0) ry[ci * 6 + wv] = v;
  }
  __syncthreads();
  if (tid == 0) {
    #pragma unroll
    for (int ci = 0; ci < 6; ++ci) {
      float s = 0.0f;
      for (int w2 = 0; w2 < 6; ++w2) s += ry[ci * 6 + w2];
      ws->yolo[ci] = s;
    }
  }
}

// ---------------- Kernel B: per-pixel step scan -> per-step delta partials ----------------
// scratch layout (transposed): scratch[e * NBMAX + bk]
__global__ __launch_bounds__(256) void yolo_kB(const float* __restrict__ depth,
                                               const WS* __restrict__ ws,
                                               float* __restrict__ scratch,
                                               int nblocks){
  __shared__ unsigned s_meta[NSTEP];
  __shared__ float    s_lv[NSTEP];
  __shared__ unsigned s_fx[NSTEP], s_fy[NSTEP], s_sx[NSTEP], s_sy[NSTEP];
  __shared__ float    acc[NE];
  int tid = threadIdx.x;
  for (int e = tid; e < NSTEP; e += 256) {
    s_meta[e] = ws->meta[e]; s_lv[e] = ws->lv[e];
    s_fx[e] = ws->fx[e]; s_fy[e] = ws->fy[e];
    s_sx[e] = ws->sx[e]; s_sy[e] = ws->sy[e];
  }
  for (int e = tid; e < NE; e += 256) acc[e] = 0.0f;
  __syncthreads();

  int c = tid;           // column = lane-contiguous
  int ln = tid & 63;
  for (int ru = blockIdx.x; ru < BN * IMGN; ru += gridDim.x) {
    int b = ru >> 8;     // row unit: b*256 + r
    int r = ru & 255;
    float dt = depth[(size_t)ru * IMGN + c];
    bool ok = dt >= 1.0f;
    float ldt = ok ? logf(dt) : 0.0f;
    bool hF = false, hS = false;
    float lvF = 0.0f, lvS = 0.0f;
    // steps of batch b are exactly t ≡ b (mod BN) in scan order
    for (int t = b; t < NSTEP; t += BN) {
      unsigned mt = s_meta[t];
      if (!(mt >> 8)) continue;                               // invalid step
      unsigned fx = s_fx[t], sx = s_sx[t];
      bool rowF = (r >= (int)(fx & 0xffff)) && (r < (int)(fx >> 16));
      bool rowS = (r >= (int)(sx & 0xffff)) && (r < (int)(sx >> 16));
      if (!rowF && !rowS) continue;                           // wave-uniform skip
      unsigned fy = s_fy[t], sy = s_sy[t];
      float lv = s_lv[t];
      bool inF = ok && rowF && (c >= (int)(fy & 0xffff)) && (c < (int)(fy >> 16));
      bool inS = ok && rowS && (c >= (int)(sy & 0xffff)) && (c < (int)(sy >> 16));
      if (__ballot(inF || inS) == 0ull) continue;
      // first-paint counts via ballot (uses pre-update hF/hS)
      unsigned long long mF = __ballot(inF && !hF);
      unsigned long long mS = __ballot(inS && !hS);
      float d1 = 0.f, d2 = 0.f, e1 = 0.f, e2 = 0.f;
      if (inF) {
        float gn = lv - ldt;
        if (hF) { float go = lvF - ldt; d1 = lv - lvF; d2 = gn * gn - go * go; }
        else    { d1 = gn; d2 = gn * gn; hF = true; }
        lvF = lv;
      }
      if (inS) {
        float gn = lv - ldt;
        if (hS) { float go = lvS - ldt; e1 = lv - lvS; e2 = gn * gn - go * go; }
        else    { e1 = gn; e2 = gn * gn; hS = true; }
        lvS = lv;
      }
      d1 = wredf(d1); d2 = wredf(d2);
      e1 = wredf(e1); e2 = wredf(e2);
      if (ln == 0) {
        atomicAdd(&acc[t * 6 + 0], (float)__popcll(mF));
        atomicAdd(&acc[t * 6 + 1], d1);
        atomicAdd(&acc[t * 6 + 2], d2);
        atomicAdd(&acc[t * 6 + 3], (float)__popcll(mS));
        atomicAdd(&acc[t * 6 + 4], e1);
        atomicAdd(&acc[t * 6 + 5], e2);
      }
    }
  }
  __syncthreads();
  // transposed scatter-write: stores are fire-and-forget, hidden by TLP
  for (int e = tid; e < NE; e += 256)
    scratch[(size_t)e * NBMAX + blockIdx.x] = acc[e];
}

// ---------------- Kernel R: parallel reduce over kB blocks (coalesced) ----------------
__global__ __launch_bounds__(256) void yolo_kR(const float* __restrict__ scratch,
                                               int nblocks,
                                               double* __restrict__ reduced){
  int w = threadIdx.x >> 6, ln = threadIdx.x & 63;
  int e = blockIdx.x * 4 + w;            // grid = NE/4 = 576
  double s = 0.0;
  for (int bk = ln; bk < nblocks; bk += 64)
    s += (double)scratch[(size_t)e * NBMAX + bk];
  s = wredd(s);
  if (ln == 0) reduced[e] = s;
}

// ---------------- Kernel C: prefix over steps, per-step SILog, final loss ----------------
__global__ __launch_bounds__(384) void yolo_kC(const WS* __restrict__ ws,
                                               const double* __restrict__ reduced,
                                               float* __restrict__ out){
  __shared__ double sd[NE];
  __shared__ double chunk[6 * 6];     // [chunkIdx][comp], chunks of 64 steps
  __shared__ double rl[6], rc[6];
  int tid = threadIdx.x;
  for (int e = tid; e < NE; e += 384) sd[e] = reduced[e];
  __syncthreads();
  if (tid < 36) {
    int ch = tid / 6, comp = tid % 6;
    double s = 0.0;
    for (int t = ch * 64; t < ch * 64 + 64; ++t) s += sd[t * 6 + comp];
    chunk[tid] = s;
  }
  __syncthreads();

  int t = tid;
  int ch = t >> 6;
  double P[6];
  #pragma unroll
  for (int comp = 0; comp < 6; ++comp) {
    double s = 0.0;
    for (int cc = 0; cc < ch; ++cc) s += chunk[cc * 6 + comp];
    for (int tt = (ch << 6); tt <= t; ++tt) s += sd[tt * 6 + comp];
    P[comp] = s;   // inclusive prefix: sums AFTER step t's paint
  }
  bool valid = ((ws->meta[t] >> 8) & 1u) != 0u;
  double lossd = 0.0, cntd = 0.0;
  {
    double n = P[0], Sg = P[1], Sg2 = P[2];
    double mean = Sg / fmax(n, 1.0);
    double var = (Sg2 - 2.0 * mean * Sg + n * mean * mean) / fmax(n - 1.0, 1.0);
    double Dg = var + 0.15 * mean * mean;
    double pl = 10.0 * sqrt(fmax(Dg, 1e-30));
    if (valid && n >= 2.0) { lossd += pl; cntd += 1.0; }
  }
  {
    double n = P[3], Sg = P[4], Sg2 = P[5];
    double mean = Sg / fmax(n, 1.0);
    double var = (Sg2 - 2.0 * mean * Sg + n * mean * mean) / fmax(n - 1.0, 1.0);
    double Dg = var + 0.15 * mean * mean;
    double pl = 10.0 * sqrt(fmax(Dg, 1e-30));
    if (valid && n >= 2.0) { lossd += pl; cntd += 1.0; }
  }
  int wv = tid >> 6, ln = tid & 63;
  double L = wredd(lossd), C = wredd(cntd);
  if (ln == 0) { rl[wv] = L; rc[wv] = C; }
  __syncthreads();
  if (tid == 0) {
    double totL = 0.0, totC = 0.0;
    for (int i = 0; i < 6; ++i) { totL += rl[i]; totC += rc[i]; }
    float dl = (float)(totL / fmax(totC, 1.0));
    float nobj = fmaxf(ws->yolo[0], 1.0f);
    float noo  = ws->yolo[1] / fmaxf(ws->yolo[2], 1.0f);
    float objl = ws->yolo[3] / nobj;
    float boxl = ws->yolo[4] / (nobj * 4.0f);
    float clsl = ws->yolo[5] / nobj;
    out[0] = 10.0f * boxl + objl + 10.0f * noo + clsl + dl;
  }
}

extern "C" void kernel_launch(void* const* d_in, const int* in_sizes, int n_in,
                              void* d_out, int out_size, void* d_ws, size_t ws_size,
                              hipStream_t stream) {
  const float* pred  = (const float*)d_in[0];
  const float* tgt   = (const float*)d_in[1];
  const float* anc   = (const float*)d_in[2];
  const float* depth = (const float*)d_in[3];
  WS* ws = (WS*)d_ws;
  size_t wsHead = ((sizeof(WS) + 255) / 256) * 256;
  float* scratch = (float*)((char*)d_ws + wsHead);
  size_t scratchBytes = (size_t)NE * NBMAX * sizeof(float);     // 4.72 MB
  double* reduced = (double*)((char*)scratch + scratchBytes);
  // workspace guard: previous round ran with 512 blocks of scratch, so ws_size
  // is >= ~4.7 MB + head; clamp block count anyway if ws is tight.
  long long avail = (long long)ws_size - (long long)wsHead - (long long)(NE * sizeof(double));
  int nblocks = NBMAX;
  if (avail < (long long)scratchBytes) {
    long long nb = avail / (long long)(NE * sizeof(float));
    nblocks = nb < 1 ? 1 : (nb > NBMAX ? NBMAX : (int)nb);
  }

  hipLaunchKernelGGL(yolo_kA, dim3(1), dim3(384), 0, stream, pred, tgt, anc, ws);
  hipLaunchKernelGGL(yolo_kB, dim3(nblocks), dim3(256), 0, stream, depth, ws, scratch, nblocks);
  hipLaunchKernelGGL(yolo_kR, dim3(NE / 4), dim3(256), 0, stream, scratch, nblocks, reduced);
  hipLaunchKernelGGL(yolo_kC, dim3(1), dim3(384), 0, stream, ws, reduced, (float*)d_out);
}

// Round 3
// 170.037 us; speedup vs baseline: 5.6566x; 1.0951x over previous
//
#include <hip/hip_runtime.h>
#include <cmath>

#define BN 2
#define AN 3
#define SN 8
#define CN 20
#define IMGN 256
#define NSTEP 384   // A*S*S*B steps in scan order (k,i,j,b)
#define PRED_C 26   // 6 + C
#define NE (NSTEP * 6)
#define NBMAX 512

__device__ __forceinline__ float wredf(float v){
  #pragma unroll
  for (int o = 32; o; o >>= 1) v += __shfl_xor(v, o);
  return v;
}
__device__ __forceinline__ double wredd(double v){
  #pragma unroll
  for (int o = 32; o; o >>= 1) v += __shfl_xor(v, o);
  return v;
}
__device__ __forceinline__ int finitef(float x){
  return (__float_as_uint(x) & 0x7f800000u) != 0x7f800000u;
}
// exact replica of reference _axis_mask index computation (f32 trunc + negative wrap)
__device__ __forceinline__ unsigned axism(float lo, float hi){
  float lof = truncf(fminf(fmaxf(lo, -1e9f), 1e9f));
  float hif = truncf(fminf(fmaxf(hi, -1e9f), 1e9f));
  int l = (int)lof, h = (int)hif;
  l = (l < 0) ? max(IMGN + l, 0) : min(l, IMGN);
  h = (h < 0) ? max(IMGN + h, 0) : min(h, IMGN);
  return (unsigned)l | ((unsigned)h << 16);
}

// per-step scan parameters; scan order t = ((k*S + i)*S + j)*B + b
__device__ __forceinline__ void step_params(int t, const float* __restrict__ pred,
                                            const float* __restrict__ anc,
                                            unsigned* valid, float* lv,
                                            unsigned* fx, unsigned* fy,
                                            unsigned* sx, unsigned* sy){
  int b = t % BN;
  int j = (t / BN) % SN;
  int i = (t / (BN * SN)) % SN;
  int k = t / (BN * SN * SN);
  const float* pc = pred + (size_t)((((b * AN + k) * SN + i) * SN + j)) * PRED_C;
  float x = pc[1], y = pc[2], wv = pc[3], hv = pc[4], v = pc[5];
  float aw = anc[2 * k], ah = anc[2 * k + 1];
  // xy gets sigmoid applied (k+2) times total (1 before loop + k+1 in loop)
  for (int m = 0; m < k + 2; ++m) {
    x = 1.0f / (1.0f + expf(-x));
    y = 1.0f / (1.0f + expf(-y));
  }
  // wh: (k+1) iterations of exp(.)*anchor[k], in f32 (overflow -> inf -> invalid)
  for (int m = 0; m < k + 1; ++m) {
    wv = expf(wv) * aw;
    hv = expf(hv) * ah;
  }
  float cx = (x + (float)j) / 8.0f * 256.0f;
  float cy = (y + (float)i) / 8.0f * 256.0f;
  float w  = wv / 8.0f * 256.0f;
  float h  = hv / 8.0f * 256.0f;
  *valid = (w > 0.0f) && (h > 0.0f) && finitef(w) && finitef(h);
  *lv = logf(fmaxf(1.0f, v));
  // NOTE reference quirk: x-mask (from cx,w) indexes dp's ROW axis, y-mask the COL axis
  *fx = axism(cx - w / 2.0f, cx + w / 2.0f);
  *fy = axism(cy - h / 2.0f, cy + h / 2.0f);
  *sx = axism(cx - w / 4.0f, cx + w / 4.0f);
  *sy = axism(cy - h / 4.0f, cy + h / 4.0f);
}

// ---------------- Kernel B: per-pixel step scan -> per-step delta partials ----------------
// scratch layout (contiguous per block): scratch[bk * NE + e]
__global__ __launch_bounds__(256) void yolo_kB(const float* __restrict__ pred,
                                               const float* __restrict__ anc,
                                               const float* __restrict__ depth,
                                               float* __restrict__ scratch){
  __shared__ unsigned s_valid[NSTEP];
  __shared__ float    s_lv[NSTEP];
  __shared__ unsigned s_fx[NSTEP], s_fy[NSTEP], s_sx[NSTEP], s_sy[NSTEP];
  __shared__ float    acc[4][NE];            // per-wave slices, no atomics
  int tid = threadIdx.x;

  // step params, computed redundantly per block (~1.5 steps/thread, trivial)
  for (int t = tid; t < NSTEP; t += 256) {
    unsigned vld, fx, fy, sx, sy; float lv;
    step_params(t, pred, anc, &vld, &lv, &fx, &fy, &sx, &sy);
    s_valid[t] = vld; s_lv[t] = lv;
    s_fx[t] = fx; s_fy[t] = fy; s_sx[t] = sx; s_sy[t] = sy;
  }
  for (int e = tid; e < 4 * NE; e += 256) (&acc[0][0])[e] = 0.0f;
  __syncthreads();

  int c = tid;           // column = lane-contiguous
  int ln = tid & 63, w = tid >> 6;
  for (int ru = blockIdx.x; ru < BN * IMGN; ru += gridDim.x) {
    int b = ru >> 8;     // row unit: b*256 + r
    int r = ru & 255;
    float dt = depth[(size_t)ru * IMGN + c];
    bool ok = dt >= 1.0f;
    float ldt = ok ? logf(dt) : 0.0f;
    bool hF = false, hS = false;
    float lvF = 0.0f, lvS = 0.0f;
    // steps of batch b are exactly t ≡ b (mod BN) in scan order
    for (int t = b; t < NSTEP; t += BN) {
      if (!s_valid[t]) continue;                              // block-uniform skip
      unsigned fx = s_fx[t], sx = s_sx[t];
      bool rowF = (r >= (int)(fx & 0xffff)) && (r < (int)(fx >> 16));
      bool rowS = (r >= (int)(sx & 0xffff)) && (r < (int)(sx >> 16));
      if (!rowF && !rowS) continue;                           // block-uniform skip
      unsigned fy = s_fy[t], sy = s_sy[t];
      float lv = s_lv[t];
      bool inF = ok && rowF && (c >= (int)(fy & 0xffff)) && (c < (int)(fy >> 16));
      bool inS = ok && rowS && (c >= (int)(sy & 0xffff)) && (c < (int)(sy >> 16));
      if (__ballot(inF || inS) == 0ull) continue;
      // first-paint counts via ballot (uses pre-update hF/hS)
      unsigned long long mF = __ballot(inF && !hF);
      unsigned long long mS = __ballot(inS && !hS);
      float d1 = 0.f, d2 = 0.f, e1 = 0.f, e2 = 0.f;
      if (inF) {
        float gn = lv - ldt;
        if (hF) { float go = lvF - ldt; d1 = lv - lvF; d2 = gn * gn - go * go; }
        else    { d1 = gn; d2 = gn * gn; hF = true; }
        lvF = lv;
      }
      if (inS) {
        float gn = lv - ldt;
        if (hS) { float go = lvS - ldt; e1 = lv - lvS; e2 = gn * gn - go * go; }
        else    { e1 = gn; e2 = gn * gn; hS = true; }
        lvS = lv;
      }
      d1 = wredf(d1); d2 = wredf(d2);
      e1 = wredf(e1); e2 = wredf(e2);
      if (ln == 0) {
        acc[w][t * 6 + 0] += (float)__popcll(mF);
        acc[w][t * 6 + 1] += d1;
        acc[w][t * 6 + 2] += d2;
        acc[w][t * 6 + 3] += (float)__popcll(mS);
        acc[w][t * 6 + 4] += e1;
        acc[w][t * 6 + 5] += e2;
      }
    }
  }
  __syncthreads();
  // contiguous coalesced write: 9216 B per block
  for (int e = tid; e < NE; e += 256)
    scratch[(size_t)blockIdx.x * NE + e] =
        acc[0][e] + acc[1][e] + acc[2][e] + acc[3][e];
}

// ---------------- Kernel R: parallel reduce over kB blocks ----------------
// one wave per element e; lanes stride over blocks (reads served by L2/L3)
__global__ __launch_bounds__(256) void yolo_kR(const float* __restrict__ scratch,
                                               int nblocks,
                                               double* __restrict__ reduced){
  int w = threadIdx.x >> 6, ln = threadIdx.x & 63;
  int e = blockIdx.x * 4 + w;            // grid = NE/4 = 576
  double s = 0.0;
  for (int bk = ln; bk < nblocks; bk += 64)
    s += (double)scratch[(size_t)bk * NE + e];
  s = wredd(s);
  if (ln == 0) reduced[e] = s;
}

// ---------------- Kernel C: YOLO losses + prefix over steps + final loss ----------------
__global__ __launch_bounds__(384) void yolo_kC(const float* __restrict__ pred,
                                               const float* __restrict__ tgt,
                                               const float* __restrict__ anc,
                                               const double* __restrict__ reduced,
                                               float* __restrict__ out){
  __shared__ double sd[NE];
  __shared__ double chunk[6 * 6];     // [chunkIdx][comp], chunks of 64 steps
  __shared__ double rl[6], rc[6];
  __shared__ float  ry[6 * 6];
  int tid = threadIdx.x;
  for (int e = tid; e < NE; e += 384) sd[e] = reduced[e];

  // ---- YOLO losses; cell order (b,a,i,j) ----
  float s_obj, s_bce, s_bcecnt, s_objls, s_boxls, s_clsls;
  {
    int t = tid;
    int j = t % SN;
    int i = (t / SN) % SN;
    int a = (t / (SN * SN)) % AN;
    int b = t / (SN * SN * AN);
    const float* pc = pred + (size_t)((((b * AN + a) * SN + i) * SN + j)) * PRED_C;
    const float* tc = tgt  + (size_t)((((b * AN + a) * SN + i) * SN + j)) * 6;
    float t0 = tc[0];
    float objf  = (t0 == 1.0f) ? 1.0f : 0.0f;
    float noobj = (t0 == 0.0f) ? 1.0f : 0.0f;
    float p0 = pc[0];
    float l = fmaxf(p0, 0.0f) - p0 * t0 + log1pf(expf(-fabsf(p0)));
    s_bce = l * noobj; s_bcecnt = noobj; s_obj = objf;
    float aw = anc[2 * a], ah = anc[2 * a + 1];
    float sxp = 1.0f / (1.0f + expf(-pc[1]));
    float syp = 1.0f / (1.0f + expf(-pc[2]));
    float bw = expf(pc[3]) * aw, bh = expf(pc[4]) * ah;
    float ax1 = sxp - bw * 0.5f, ax2 = sxp + bw * 0.5f;
    float ay1 = syp - bh * 0.5f, ay2 = syp + bh * 0.5f;
    float bx1 = tc[1] - tc[3] * 0.5f, bx2 = tc[1] + tc[3] * 0.5f;
    float by1 = tc[2] - tc[4] * 0.5f, by2 = tc[2] + tc[4] * 0.5f;
    float iw = fmaxf(fminf(ax2, bx2) - fmaxf(ax1, bx1), 0.0f);
    float ih = fmaxf(fminf(ay2, by2) - fmaxf(ay1, by1), 0.0f);
    float inter = iw * ih;
    float areaA = fabsf((ax2 - ax1) * (ay2 - ay1));
    float areaB = fabsf((bx2 - bx1) * (by2 - by1));
    float iou = inter / (areaA + areaB - inter + 1e-6f);
    float sp0 = 1.0f / (1.0f + expf(-p0));
    float od = sp0 - iou * t0;
    s_objls = od * od * objf;
    float dx = sxp - tc[1], dy = syp - tc[2];
    float dw = pc[3] - logf(1e-16f + tc[3] / aw);
    float dh = pc[4] - logf(1e-16f + tc[4] / ah);
    s_boxls = (dx * dx + dy * dy + dw * dw + dh * dh) * objf;
    int lbl = (int)tc[5];
    float mx = -INFINITY;
    for (int c = 0; c < CN; ++c) mx = fmaxf(mx, pc[6 + c]);
    float se = 0.0f;
    for (int c = 0; c < CN; ++c) se += expf(pc[6 + c] - mx);
    float nll = mx + logf(se) - pc[6 + lbl];
    s_clsls = nll * objf;
  }
  {
    int wv = tid >> 6, ln = tid & 63;
    float vals[6] = { s_obj, s_bce, s_bcecnt, s_objls, s_boxls, s_clsls };
    #pragma unroll
    for (int ci = 0; ci < 6; ++ci) {
      float v = wredf(vals[ci]);
      if (ln == 0) ry[ci * 6 + wv] = v;
    }
  }

  // ---- valid bit for step tid (recomputed; only w/h chain matters) ----
  unsigned vld, ufx, ufy, usx, usy; float ulv;
  step_params(tid, pred, anc, &vld, &ulv, &ufx, &ufy, &usx, &usy);

  __syncthreads();
  if (tid < 36) {
    int ch = tid / 6, comp = tid % 6;
    double s = 0.0;
    for (int t = ch * 64; t < ch * 64 + 64; ++t) s += sd[t * 6 + comp];
    chunk[tid] = s;
  }
  __syncthreads();

  int t = tid;
  int ch = t >> 6;
  double P[6];
  #pragma unroll
  for (int comp = 0; comp < 6; ++comp) {
    double s = 0.0;
    for (int cc = 0; cc < ch; ++cc) s += chunk[cc * 6 + comp];
    for (int tt = (ch << 6); tt <= t; ++tt) s += sd[tt * 6 + comp];
    P[comp] = s;   // inclusive prefix: sums AFTER step t's paint
  }
  double lossd = 0.0, cntd = 0.0;
  {
    double n = P[0], Sg = P[1], Sg2 = P[2];
    double mean = Sg / fmax(n, 1.0);
    double var = (Sg2 - 2.0 * mean * Sg + n * mean * mean) / fmax(n - 1.0, 1.0);
    double Dg = var + 0.15 * mean * mean;
    double pl = 10.0 * sqrt(fmax(Dg, 1e-30));
    if (vld && n >= 2.0) { lossd += pl; cntd += 1.0; }
  }
  {
    double n = P[3], Sg = P[4], Sg2 = P[5];
    double mean = Sg / fmax(n, 1.0);
    double var = (Sg2 - 2.0 * mean * Sg + n * mean * mean) / fmax(n - 1.0, 1.0);
    double Dg = var + 0.15 * mean * mean;
    double pl = 10.0 * sqrt(fmax(Dg, 1e-30));
    if (vld && n >= 2.0) { lossd += pl; cntd += 1.0; }
  }
  int wv = tid >> 6, ln = tid & 63;
  double L = wredd(lossd), C = wredd(cntd);
  if (ln == 0) { rl[wv] = L; rc[wv] = C; }
  __syncthreads();
  if (tid == 0) {
    double totL = 0.0, totC = 0.0;
    for (int i = 0; i < 6; ++i) { totL += rl[i]; totC += rc[i]; }
    float yolo[6];
    #pragma unroll
    for (int ci = 0; ci < 6; ++ci) {
      float s = 0.0f;
      for (int w2 = 0; w2 < 6; ++w2) s += ry[ci * 6 + w2];
      yolo[ci] = s;
    }
    float dl = (float)(totL / fmax(totC, 1.0));
    float nobj = fmaxf(yolo[0], 1.0f);
    float noo  = yolo[1] / fmaxf(yolo[2], 1.0f);
    float objl = yolo[3] / nobj;
    float boxl = yolo[4] / (nobj * 4.0f);
    float clsl = yolo[5] / nobj;
    out[0] = 10.0f * boxl + objl + 10.0f * noo + clsl + dl;
  }
}

extern "C" void kernel_launch(void* const* d_in, const int* in_sizes, int n_in,
                              void* d_out, int out_size, void* d_ws, size_t ws_size,
                              hipStream_t stream) {
  const float* pred  = (const float*)d_in[0];
  const float* tgt   = (const float*)d_in[1];
  const float* anc   = (const float*)d_in[2];
  const float* depth = (const float*)d_in[3];

  float* scratch = (float*)d_ws;
  long long avail = (long long)ws_size - (long long)(NE * sizeof(double));
  int nblocks = NBMAX;
  long long need = (long long)NBMAX * NE * (long long)sizeof(float);
  if (avail < need) {
    long long nb = avail / (long long)(NE * sizeof(float));
    nblocks = nb < 1 ? 1 : (nb > NBMAX ? NBMAX : (int)nb);
  }
  double* reduced = (double*)((char*)d_ws + (size_t)nblocks * NE * sizeof(float));

  hipLaunchKernelGGL(yolo_kB, dim3(nblocks), dim3(256), 0, stream, pred, anc, depth, scratch);
  hipLaunchKernelGGL(yolo_kR, dim3(NE / 4), dim3(256), 0, stream, scratch, nblocks, reduced);
  hipLaunchKernelGGL(yolo_kC, dim3(1), dim3(384), 0, stream, pred, tgt, anc, reduced, (float*)d_out);
}